// Round 9
// baseline (414.096 us; speedup 1.0000x reference)
//
#include <hip/hip_runtime.h>
#include <hip/hip_bf16.h>

typedef __attribute__((ext_vector_type(8))) short short8;
typedef __attribute__((ext_vector_type(8))) unsigned short ushort8;
typedef __attribute__((ext_vector_type(4))) unsigned short ushort4v;
typedef __attribute__((ext_vector_type(4))) float f32x4;

#define NTOK 5120
#define DDIM 256

__device__ __forceinline__ unsigned short f2bf(float f) {
  union { float f; unsigned int u; } x; x.f = f;
  unsigned int r = x.u + 0x7FFFu + ((x.u >> 16) & 1u);
  return (unsigned short)(r >> 16);
}
__device__ __forceinline__ float bf2f(unsigned short u) {
  union { unsigned int i; float f; } x; x.i = ((unsigned int)u) << 16; return x.f;
}

// ---------------- Kernel 1: depthwise conv Q,K + unfold -> token-major bf16 [b][5120][256]
__global__ __launch_bounds__(256) void qk_gen(
    const float* __restrict__ xin, const float* __restrict__ wq,
    const float* __restrict__ bq, const float* __restrict__ wk,
    const float* __restrict__ bk, unsigned short* __restrict__ qt,
    unsigned short* __restrict__ kt)
{
  const int ch = blockIdx.x;   // 0..63
  const int bt = blockIdx.y;   // 0..9
  const int b = bt / 5, tf = bt % 5;
  const int tid = threadIdx.x;
  const float* xp = xin + ((size_t)bt * 64 + ch) * 4096;
  float wqv[9], wkv[9];
  #pragma unroll
  for (int i = 0; i < 9; i++) { wqv[i] = wq[ch * 9 + i]; wkv[i] = wk[ch * 9 + i]; }
  const float bqv = bq[ch], bkv = bk[ch];

  #pragma unroll
  for (int p = 0; p < 4; p++) {
    int pid = tid + p * 256;         // patch id in frame (gy*32+gx)
    int gy = pid >> 5, gx = pid & 31;
    float v[4][4];
    #pragma unroll
    for (int r = 0; r < 4; r++) {
      int yy = 2 * gy - 1 + r;
      #pragma unroll
      for (int cc = 0; cc < 4; cc++) {
        int xx = 2 * gx - 1 + cc;
        bool ok = (yy >= 0) && (yy < 64) && (xx >= 0) && (xx < 64);
        v[r][cc] = ok ? xp[yy * 64 + xx] : 0.f;
      }
    }
    unsigned short qo[4], ko[4];
    #pragma unroll
    for (int py = 0; py < 2; py++)
      #pragma unroll
      for (int px = 0; px < 2; px++) {
        float aq = bqv, ak = bkv;
        #pragma unroll
        for (int dy = 0; dy < 3; dy++)
          #pragma unroll
          for (int dx = 0; dx < 3; dx++) {
            float xv = v[py + dy][px + dx];
            aq += wqv[dy * 3 + dx] * xv;
            ak += wkv[dy * 3 + dx] * xv;
          }
        qo[py * 2 + px] = f2bf(aq);
        ko[py * 2 + px] = f2bf(ak);
      }
    size_t base = ((size_t)(b * NTOK + tf * 1024 + pid)) * DDIM + ch * 4;
    ushort4v qv = { qo[0], qo[1], qo[2], qo[3] };
    ushort4v kv = { ko[0], ko[1], ko[2], ko[3] };
    *(ushort4v*)(qt + base) = qv;
    *(ushort4v*)(kt + base) = kv;
  }
}

// ---------------- weight transform: wv/wc [co][ci][9] f32 -> [tap][co][ci] bf16
__global__ __launch_bounds__(256) void wt_gen(
    const float* __restrict__ w0, const float* __restrict__ w1,
    unsigned short* __restrict__ o0, unsigned short* __restrict__ o1)
{
  const int tap = blockIdx.x;            // 0..8
  const float* src = blockIdx.y ? w1 : w0;
  unsigned short* dst = blockIdx.y ? o1 : o0;
  const int t = threadIdx.x;
  #pragma unroll
  for (int i = 0; i < 16; i++) {
    int oi = t + i * 256;                // co*64+ci
    dst[tap * 4096 + oi] = f2bf(src[(size_t)oi * 9 + tap]);
  }
}

// ---------------- implicit-GEMM MFMA conv: 3x3 SAME, 64ci->64co, fused epilogue
// grid (strip=32, bt=10); WG = 4 waves: wave (ry=sw>>1 [2 rows], ch=sw&1 [co half])
// MODE 0: out = conv+bias -> vt bf16 d-major [b][256][5120]
// MODE 1: out = conv+bias+resid -> dstf f32 [bt][64][64][64]
template<int MODE>
__global__ __launch_bounds__(256) void conv_mfma(
    const float* __restrict__ src, const unsigned short* __restrict__ wt,
    const float* __restrict__ bias, const float* __restrict__ resid,
    float* __restrict__ dstf, unsigned short* __restrict__ vt)
{
  const int strip = blockIdx.x;  // 0..31
  const int bt = blockIdx.y;     // 0..9
  const int y0 = strip * 2;
  const int tid = threadIdx.x;
  const int sw = tid >> 6, lane = tid & 63;
  const int ry = sw >> 1, ch = sw & 1;
  const int g = lane >> 4, c = lane & 15;

  __shared__ __align__(16) unsigned short lds_in[4 * 66 * 64]; // [row][lcol][ci] slot^=(lcol&7)
  __shared__ __align__(16) unsigned short lds_w[64 * 64];      // [co][ci] slot^=(co&7)

  // ---- stage input rows y0-1..y0+2; wave sw -> ci block sw*16..+15 (8 pairs)
  {
    const int rr = lane >> 4;          // 0..3
    const int cb = lane & 15;          // 4 cols each
    const int row = y0 - 1 + rr;
    const bool rok = (row >= 0) && (row < 64);
    #pragma unroll
    for (int pp = 0; pp < 8; ++pp) {
      const int ci0 = sw * 16 + pp * 2;
      f32x4 va = { 0.f, 0.f, 0.f, 0.f }, vb = { 0.f, 0.f, 0.f, 0.f };
      if (rok) {
        va = *(const f32x4*)(src + ((size_t)(bt * 64 + ci0)) * 4096 + row * 64 + cb * 4);
        vb = *(const f32x4*)(src + ((size_t)(bt * 64 + ci0 + 1)) * 4096 + row * 64 + cb * 4);
      }
      char* rbase = (char*)lds_in + (rr * 66) * 128 + (ci0 & 7) * 2;
      const int sl = ci0 >> 3;
      #pragma unroll
      for (int q = 0; q < 4; ++q) {
        int lcol = cb * 4 + q + 1;
        unsigned int pk = (unsigned int)f2bf(va[q]) | ((unsigned int)f2bf(vb[q]) << 16);
        *(unsigned int*)(rbase + lcol * 128 + ((sl ^ (lcol & 7)) * 16)) = pk;
      }
      if (cb == 0)  *(unsigned int*)(rbase + ((sl ^ 0) * 16)) = 0u;              // lcol 0
      if (cb == 15) *(unsigned int*)(rbase + 65 * 128 + ((sl ^ 1) * 16)) = 0u;   // lcol 65
    }
  }

  f32x4 acc[2][4];
  #pragma unroll
  for (int ct = 0; ct < 2; ct++)
    #pragma unroll
    for (int xt = 0; xt < 4; xt++) acc[ct][xt] = (f32x4){ 0.f, 0.f, 0.f, 0.f };

  #pragma unroll 1
  for (int tap = 0; tap < 9; ++tap) {
    __syncthreads();   // prior readers done (tap 0: input staging fence)
    {
      const unsigned short* wp = wt + tap * 4096;
      #pragma unroll
      for (int h = 0; h < 2; ++h) {
        int el = h * 2048 + tid * 8;
        int co = el >> 6, sl = (el & 63) >> 3;
        short8 wv8 = *(const short8*)(wp + el);
        *(short8*)((char*)lds_w + co * 128 + ((sl ^ (co & 7)) * 16)) = wv8;
      }
    }
    __syncthreads();
    const int dy = tap / 3 - 1, dx = tap % 3 - 1;
    const int rowp = ry + 1 + dy;       // 0..3
    #pragma unroll
    for (int kblk = 0; kblk < 2; ++kblk) {
      short8 af[2], bf[4];
      #pragma unroll
      for (int ct = 0; ct < 2; ++ct) {
        int co = ch * 32 + ct * 16 + c;
        af[ct] = *(const short8*)((char*)lds_w + co * 128 + (((kblk * 4 + g) ^ (co & 7)) * 16));
      }
      #pragma unroll
      for (int xt = 0; xt < 4; ++xt) {
        int lcol = xt * 16 + c + dx + 1;
        bf[xt] = *(const short8*)((char*)lds_in + (rowp * 66 + lcol) * 128 + (((kblk * 4 + g) ^ (lcol & 7)) * 16));
      }
      #pragma unroll
      for (int ct = 0; ct < 2; ++ct)
        #pragma unroll
        for (int xt = 0; xt < 4; ++xt)
          acc[ct][xt] = __builtin_amdgcn_mfma_f32_16x16x32_bf16(af[ct], bf[xt], acc[ct][xt], 0, 0, 0);
    }
  }

  // ---- fused epilogue: lane holds C[co=ch*32+ct*16+4g+r][x=xt*16+c], row y
  const int y = y0 + ry;
  if (MODE == 0) {
    const int b = bt / 5, tf = bt % 5;
    const int py = y & 1, gy = y >> 1;
    #pragma unroll
    for (int ct = 0; ct < 2; ++ct)
      #pragma unroll
      for (int r = 0; r < 4; ++r) {
        const int co = ch * 32 + ct * 16 + g * 4 + r;
        const float bv = bias[co];
        #pragma unroll
        for (int xt = 0; xt < 4; ++xt) {
          int x = xt * 16 + c;
          int d = co * 4 + py * 2 + (x & 1);
          int tok = tf * 1024 + gy * 32 + (x >> 1);
          vt[((size_t)(b * DDIM + d)) * NTOK + tok] = f2bf(acc[ct][xt][r] + bv);
        }
      }
  } else {
    #pragma unroll
    for (int ct = 0; ct < 2; ++ct)
      #pragma unroll
      for (int r = 0; r < 4; ++r) {
        const int co = ch * 32 + ct * 16 + g * 4 + r;
        const float bv = bias[co];
        const size_t rowb = ((size_t)(bt * 64 + co)) * 4096 + (size_t)y * 64;
        #pragma unroll
        for (int xt = 0; xt < 4; ++xt) {
          int x = xt * 16 + c;
          dstf[rowb + x] = acc[ct][xt][r] + bv + resid[rowb + x];
        }
      }
  }
}

// ---------------- flash attention partials: 2 i-strips/wave, P overlaid on lds_k (64KB LDS)
// Register-prefetch double buffer: next tile's K/V loads issue right after staging barrier,
// consumed at next iteration's reg->LDS write. po: f32 [row][d] (R4-proven layout).
__global__ __launch_bounds__(256, 2) void attn_kernel(
    const unsigned short* __restrict__ qt, const unsigned short* __restrict__ kt,
    const unsigned short* __restrict__ vt, float* __restrict__ po,
    float* __restrict__ pm, float* __restrict__ pl, int jchunk)
{
  const int b = blockIdx.z;
  const int jc = blockIdx.y;
  const int njc = gridDim.y;
  const int i0 = blockIdx.x * 128;
  const int tid = threadIdx.x;
  const int w = tid >> 6, lane = tid & 63;
  const int g = lane >> 4, c = lane & 15;

  __shared__ __align__(16) unsigned short lds_k[64 * 256];    // 32 KB [j][d] swizzled; P overlay
  __shared__ __align__(16) unsigned short lds_v[256 * 64];    // 32 KB [d][j] swizzled

  short8 qf[2][8];
  #pragma unroll
  for (int st = 0; st < 2; st++) {
    const unsigned short* qr = qt + ((size_t)(b * NTOK + i0 + w * 32 + st * 16 + c)) * DDIM + g * 8;
    #pragma unroll
    for (int kb = 0; kb < 8; kb++) qf[st][kb] = *(const short8*)(qr + kb * 32);
  }
  f32x4 o[32];
  #pragma unroll
  for (int i = 0; i < 32; i++) o[i] = (f32x4){ 0.f, 0.f, 0.f, 0.f };
  float m[2][4], l[2][4];
  #pragma unroll
  for (int st = 0; st < 2; st++)
    #pragma unroll
    for (int r = 0; r < 4; r++) { m[st][r] = -1e30f; l[st][r] = 0.f; }

  const int sr = tid >> 5, sc = tid & 31;
  const int vdr = tid >> 3, vcc = tid & 7;
  char* pb = (char*)lds_k + w * 4096;   // per-wave P region (overlay)

  const int jbeg = jc * jchunk;
  const int jend = jbeg + jchunk;

  // prefetch registers for next tile's K/V
  short8 kpre[8], vpre[8];
  {
    const int j0 = jbeg;
    #pragma unroll
    for (int p = 0; p < 8; p++) {
      int row = sr + p * 8;
      kpre[p] = *(const short8*)(kt + ((size_t)(b * NTOK + j0 + row)) * DDIM + sc * 8);
      int dd = vdr + p * 32;
      vpre[p] = *(const short8*)(vt + ((size_t)(b * DDIM + dd)) * NTOK + j0 + vcc * 8);
    }
  }

  for (int j0 = jbeg; j0 < jend; j0 += 64) {
    // ---- write prefetched regs -> LDS
    #pragma unroll
    for (int p = 0; p < 8; p++) {
      int row = sr + p * 8;
      *(short8*)((char*)lds_k + row * 512 + ((sc ^ (row & 7)) * 16)) = kpre[p];
      int dd = vdr + p * 32;
      *(short8*)((char*)lds_v + dd * 128 + ((vcc ^ (dd & 7)) * 16)) = vpre[p];
    }
    __syncthreads();

    // ---- issue next tile's loads (latency hides under compute below)
    if (j0 + 64 < jend) {
      const int jn = j0 + 64;
      #pragma unroll
      for (int p = 0; p < 8; p++) {
        int row = sr + p * 8;
        kpre[p] = *(const short8*)(kt + ((size_t)(b * NTOK + jn + row)) * DDIM + sc * 8);
        int dd = vdr + p * 32;
        vpre[p] = *(const short8*)(vt + ((size_t)(b * DDIM + dd)) * NTOK + jn + vcc * 8);
      }
    }

    // S = Q*K^T for both strips; one kf read feeds 2 MFMAs
    f32x4 s0[4], s1[4];
    #pragma unroll
    for (int js = 0; js < 4; js++) {
      s0[js] = (f32x4){ 0.f, 0.f, 0.f, 0.f };
      s1[js] = (f32x4){ 0.f, 0.f, 0.f, 0.f };
      int row = js * 16 + c;
      int sw2 = row & 7;
      #pragma unroll
      for (int kb = 0; kb < 8; kb++) {
        short8 kf = *(const short8*)((char*)lds_k + row * 512 + (((kb * 4 + g) ^ sw2) * 16));
        s0[js] = __builtin_amdgcn_mfma_f32_16x16x32_bf16(qf[0][kb], kf, s0[js], 0, 0, 0);
        s1[js] = __builtin_amdgcn_mfma_f32_16x16x32_bf16(qf[1][kb], kf, s1[js], 0, 0, 0);
      }
    }
    // softmax strip 0 (keep P in regs until barrier)
    float pvv[4][4], alpha[4];
    #pragma unroll
    for (int r = 0; r < 4; r++) {
      float mx = fmaxf(fmaxf(s0[0][r], s0[1][r]), fmaxf(s0[2][r], s0[3][r])) * 0.0625f;
      #pragma unroll
      for (int off = 1; off < 16; off <<= 1) mx = fmaxf(mx, __shfl_xor(mx, off));
      float mn = fmaxf(m[0][r], mx);
      alpha[r] = __expf(m[0][r] - mn);
      float p0 = __expf(s0[0][r] * 0.0625f - mn);
      float p1 = __expf(s0[1][r] * 0.0625f - mn);
      float p2 = __expf(s0[2][r] * 0.0625f - mn);
      float p3 = __expf(s0[3][r] * 0.0625f - mn);
      pvv[0][r] = p0; pvv[1][r] = p1; pvv[2][r] = p2; pvv[3][r] = p3;
      float sum = p0 + p1 + p2 + p3;
      #pragma unroll
      for (int off = 1; off < 16; off <<= 1) sum += __shfl_xor(sum, off);
      l[0][r] = l[0][r] * alpha[r] + sum;
      m[0][r] = mn;
    }
    {
      f32x4 av = { alpha[0], alpha[1], alpha[2], alpha[3] };
      #pragma unroll
      for (int ds = 0; ds < 16; ds++) o[ds] *= av;
    }
    __syncthreads();   // all waves done reading lds_k -> safe to overlay P
    // write P strip 0
    #pragma unroll
    for (int js = 0; js < 4; js++)
      #pragma unroll
      for (int r = 0; r < 4; r++) {
        int row = 4 * g + r;
        int slot = (js * 2 + (c >> 3)) ^ (row & 7);
        *(unsigned short*)(pb + row * 128 + slot * 16 + (c & 7) * 2) = f2bf(pvv[js][r]);
      }
    // softmax strip 1
    #pragma unroll
    for (int r = 0; r < 4; r++) {
      float mx = fmaxf(fmaxf(s1[0][r], s1[1][r]), fmaxf(s1[2][r], s1[3][r])) * 0.0625f;
      #pragma unroll
      for (int off = 1; off < 16; off <<= 1) mx = fmaxf(mx, __shfl_xor(mx, off));
      float mn = fmaxf(m[1][r], mx);
      alpha[r] = __expf(m[1][r] - mn);
      float p0 = __expf(s1[0][r] * 0.0625f - mn);
      float p1 = __expf(s1[1][r] * 0.0625f - mn);
      float p2 = __expf(s1[2][r] * 0.0625f - mn);
      float p3 = __expf(s1[3][r] * 0.0625f - mn);
      pvv[0][r] = p0; pvv[1][r] = p1; pvv[2][r] = p2; pvv[3][r] = p3;
      float sum = p0 + p1 + p2 + p3;
      #pragma unroll
      for (int off = 1; off < 16; off <<= 1) sum += __shfl_xor(sum, off);
      l[1][r] = l[1][r] * alpha[r] + sum;
      m[1][r] = mn;
    }
    {
      f32x4 av = { alpha[0], alpha[1], alpha[2], alpha[3] };
      #pragma unroll
      for (int ds = 0; ds < 16; ds++) o[16 + ds] *= av;
    }
    // write P strip 1
    #pragma unroll
    for (int js = 0; js < 4; js++)
      #pragma unroll
      for (int r = 0; r < 4; r++) {
        int row = 16 + 4 * g + r;
        int slot = (js * 2 + (c >> 3)) ^ (row & 7);
        *(unsigned short*)(pb + row * 128 + slot * 16 + (c & 7) * 2) = f2bf(pvv[js][r]);
      }
    // read P fragments (same-wave DS ordering guarantees write->read)
    short8 pf[2][2];
    #pragma unroll
    for (int st = 0; st < 2; st++)
      #pragma unroll
      for (int k2 = 0; k2 < 2; k2++)
        pf[st][k2] = *(short8*)(pb + (st * 16 + c) * 128 + (((k2 * 4 + g) ^ (c & 7)) * 16));
    // O += P*V; one vf read feeds 2 MFMAs
    #pragma unroll
    for (int ds = 0; ds < 16; ds++) {
      int vrow = ds * 16 + c;
      int sw2 = c & 7;
      #pragma unroll
      for (int k2 = 0; k2 < 2; k2++) {
        short8 vf = *(const short8*)((char*)lds_v + vrow * 128 + (((k2 * 4 + g) ^ sw2) * 16));
        o[ds]      = __builtin_amdgcn_mfma_f32_16x16x32_bf16(pf[0][k2], vf, o[ds], 0, 0, 0);
        o[16 + ds] = __builtin_amdgcn_mfma_f32_16x16x32_bf16(pf[1][k2], vf, o[16 + ds], 0, 0, 0);
      }
    }
    __syncthreads();   // protect lds_k (incl. P overlay) + lds_v before restage
  }
  // ---- epilogue: f32 po, [row][d] layout; each (ds,r) store = 16 lanes x 4B = 64B line
  #pragma unroll
  for (int st = 0; st < 2; st++) {
    const size_t rbase = ((size_t)(b * njc + jc)) * NTOK + i0 + w * 32 + st * 16;
    #pragma unroll
    for (int ds = 0; ds < 16; ds++)
      #pragma unroll
      for (int r = 0; r < 4; r++)
        po[(rbase + 4 * g + r) * DDIM + ds * 16 + c] = o[st * 16 + ds][r];
    if (c == 0) {
      #pragma unroll
      for (int r = 0; r < 4; r++) {
        pm[rbase + 4 * g + r] = m[st][r];
        pl[rbase + 4 * g + r] = l[st][r];
      }
    }
  }
}

// ---------------- attn combine: online LSE merge of njc f32 partials, fold into feat
__global__ __launch_bounds__(256) void attn_combine(
    const float* __restrict__ po, const float* __restrict__ pm,
    const float* __restrict__ pl, float* __restrict__ feat, int njc)
{
  const int b = blockIdx.y;
  const int i0 = blockIdx.x * 64;
  const int t = threadIdx.x;
  const int row = t >> 2, dq = (t & 3) * 64;
  const int i = i0 + row;

  float M = -1e30f, L = 0.f;
  f32x4 acc[16];
  #pragma unroll
  for (int q = 0; q < 16; q++) acc[q] = (f32x4){ 0.f, 0.f, 0.f, 0.f };

  #pragma unroll 1
  for (int jc = 0; jc < njc; jc++) {
    const size_t rb = ((size_t)(b * njc + jc)) * NTOK + i;
    float mj = pm[rb], lj = pl[rb];
    float mn = fmaxf(M, mj);
    float so = __expf(M - mn), sn = __expf(mj - mn);
    const float* pp = po + rb * DDIM + dq;
    #pragma unroll
    for (int q = 0; q < 16; q++) {
      f32x4 v = *(const f32x4*)(pp + q * 4);
      acc[q] = acc[q] * so + v * sn;
    }
    L = L * so + lj * sn;
    M = mn;
  }
  const float inv = 1.f / L;
  const int tf = i >> 10, jn = i & 1023;
  const int gy = jn >> 5, gx = jn & 31;
  const size_t fb = ((size_t)((b * 5 + tf) * 64)) * 4096 + (2 * gy) * 64 + 2 * gx;
  #pragma unroll
  for (int q = 0; q < 16; q++) {
    f32x4 a = acc[q] * inv;
    int ch = (dq + q * 4) >> 2;
    size_t base = fb + (size_t)ch * 4096;
    feat[base] = a[0]; feat[base + 1] = a[1];
    feat[base + 64] = a[2]; feat[base + 65] = a[3];
  }
}

extern "C" void kernel_launch(void* const* d_in, const int* in_sizes, int n_in,
                              void* d_out, int out_size, void* d_ws, size_t ws_size,
                              hipStream_t stream) {
  const float* x  = (const float*)d_in[0];
  const float* wq = (const float*)d_in[1];
  const float* bq = (const float*)d_in[2];
  const float* wk = (const float*)d_in[3];
  const float* bk = (const float*)d_in[4];
  const float* wv = (const float*)d_in[5];
  const float* bv = (const float*)d_in[6];
  const float* wc = (const float*)d_in[7];
  const float* bc = (const float*)d_in[8];
  float* out = (float*)d_out;

  char* ws = (char*)d_ws;
  unsigned short* qt = (unsigned short*)(ws);              //  5,242,880 B
  unsigned short* kt = (unsigned short*)(ws + 5242880);    //  5,242,880 B
  unsigned short* vt = (unsigned short*)(ws + 10485760);   //  5,242,880 B
  float*          ft = (float*)(ws + 15728640);            // 10,485,760 B
  unsigned short* wtv = (unsigned short*)(ws + 26214400);  //     73,728 B
  unsigned short* wtc = (unsigned short*)(ws + 26288128);  //     73,728 B
  const size_t big_off = 26361856;
  float* po = (float*)(ws + big_off);                      // attn partials f32 [row][d]

  // choose j-split by available workspace: po = 2*njc*5120*256*4 bytes
  int njc = 5;                       // 400 WGs: fully co-resident at 2 WG/CU, no tail
  size_t po_bytes = (size_t)2 * njc * NTOK * DDIM * 4;
  if (big_off + po_bytes + (size_t)4 * 2 * njc * NTOK > ws_size) {
    njc = 4;
    po_bytes = (size_t)2 * njc * NTOK * DDIM * 4;
  }
  float* pm = (float*)(ws + big_off + po_bytes);
  float* pl = pm + (size_t)2 * njc * NTOK;
  const int jchunk = NTOK / njc;

  wt_gen        <<<dim3(9, 2), 256, 0, stream>>>(wv, wc, wtv, wtc);
  qk_gen        <<<dim3(64, 10), 256, 0, stream>>>(x, wq, bq, wk, bk, qt, kt);
  conv_mfma<0>  <<<dim3(32, 10), 256, 0, stream>>>(x, wtv, bv, nullptr, nullptr, vt);
  attn_kernel   <<<dim3(40, njc, 2), 256, 0, stream>>>(qt, kt, vt, po, pm, pl, jchunk);
  attn_combine  <<<dim3(80, 2), 256, 0, stream>>>(po, pm, pl, ft, njc);
  conv_mfma<1>  <<<dim3(32, 10), 256, 0, stream>>>(ft, wtc, bc, x, out, nullptr);
}

// Round 10
// 405.891 us; speedup vs baseline: 1.0202x; 1.0202x over previous
//
#include <hip/hip_runtime.h>
#include <hip/hip_bf16.h>

typedef __attribute__((ext_vector_type(8))) short short8;
typedef __attribute__((ext_vector_type(8))) unsigned short ushort8;
typedef __attribute__((ext_vector_type(4))) unsigned short ushort4v;
typedef __attribute__((ext_vector_type(4))) float f32x4;

#define NTOK 5120
#define DDIM 256
#define NJC 4            // 8 (b,jc) slices == 8 XCDs

__device__ __forceinline__ unsigned short f2bf(float f) {
  union { float f; unsigned int u; } x; x.f = f;
  unsigned int r = x.u + 0x7FFFu + ((x.u >> 16) & 1u);
  return (unsigned short)(r >> 16);
}
__device__ __forceinline__ float bf2f(unsigned short u) {
  union { unsigned int i; float f; } x; x.i = ((unsigned int)u) << 16; return x.f;
}

// ---------------- Kernel 1: depthwise conv Q,K + unfold -> token-major bf16 [b][5120][256]
__global__ __launch_bounds__(256) void qk_gen(
    const float* __restrict__ xin, const float* __restrict__ wq,
    const float* __restrict__ bq, const float* __restrict__ wk,
    const float* __restrict__ bk, unsigned short* __restrict__ qt,
    unsigned short* __restrict__ kt)
{
  const int ch = blockIdx.x;   // 0..63
  const int bt = blockIdx.y;   // 0..9
  const int b = bt / 5, tf = bt % 5;
  const int tid = threadIdx.x;
  const float* xp = xin + ((size_t)bt * 64 + ch) * 4096;
  float wqv[9], wkv[9];
  #pragma unroll
  for (int i = 0; i < 9; i++) { wqv[i] = wq[ch * 9 + i]; wkv[i] = wk[ch * 9 + i]; }
  const float bqv = bq[ch], bkv = bk[ch];

  #pragma unroll
  for (int p = 0; p < 4; p++) {
    int pid = tid + p * 256;         // patch id in frame (gy*32+gx)
    int gy = pid >> 5, gx = pid & 31;
    float v[4][4];
    #pragma unroll
    for (int r = 0; r < 4; r++) {
      int yy = 2 * gy - 1 + r;
      #pragma unroll
      for (int cc = 0; cc < 4; cc++) {
        int xx = 2 * gx - 1 + cc;
        bool ok = (yy >= 0) && (yy < 64) && (xx >= 0) && (xx < 64);
        v[r][cc] = ok ? xp[yy * 64 + xx] : 0.f;
      }
    }
    unsigned short qo[4], ko[4];
    #pragma unroll
    for (int py = 0; py < 2; py++)
      #pragma unroll
      for (int px = 0; px < 2; px++) {
        float aq = bqv, ak = bkv;
        #pragma unroll
        for (int dy = 0; dy < 3; dy++)
          #pragma unroll
          for (int dx = 0; dx < 3; dx++) {
            float xv = v[py + dy][px + dx];
            aq += wqv[dy * 3 + dx] * xv;
            ak += wkv[dy * 3 + dx] * xv;
          }
        qo[py * 2 + px] = f2bf(aq);
        ko[py * 2 + px] = f2bf(ak);
      }
    size_t base = ((size_t)(b * NTOK + tf * 1024 + pid)) * DDIM + ch * 4;
    ushort4v qv = { qo[0], qo[1], qo[2], qo[3] };
    ushort4v kv = { ko[0], ko[1], ko[2], ko[3] };
    *(ushort4v*)(qt + base) = qv;
    *(ushort4v*)(kt + base) = kv;
  }
}

// ---------------- weight transform: wv/wc [co][ci][9] f32 -> [tap][co][ci] bf16
__global__ __launch_bounds__(256) void wt_gen(
    const float* __restrict__ w0, const float* __restrict__ w1,
    unsigned short* __restrict__ o0, unsigned short* __restrict__ o1)
{
  const int tap = blockIdx.x;            // 0..8
  const float* src = blockIdx.y ? w1 : w0;
  unsigned short* dst = blockIdx.y ? o1 : o0;
  const int t = threadIdx.x;
  #pragma unroll
  for (int i = 0; i < 16; i++) {
    int oi = t + i * 256;                // co*64+ci
    dst[tap * 4096 + oi] = f2bf(src[(size_t)oi * 9 + tap]);
  }
}

// ---------------- implicit-GEMM MFMA conv: 3x3 SAME, 64ci->64co, fused epilogue
// grid (strip=32, bt=10); WG = 4 waves: wave (ry=sw>>1 [2 rows], ch=sw&1 [co half])
// MODE 0: out = conv+bias -> vt bf16 d-major [b][256][5120]
// MODE 1: out = conv+bias+resid -> dstf f32 [bt][64][64][64]
template<int MODE>
__global__ __launch_bounds__(256) void conv_mfma(
    const float* __restrict__ src, const unsigned short* __restrict__ wt,
    const float* __restrict__ bias, const float* __restrict__ resid,
    float* __restrict__ dstf, unsigned short* __restrict__ vt)
{
  const int strip = blockIdx.x;  // 0..31
  const int bt = blockIdx.y;     // 0..9
  const int y0 = strip * 2;
  const int tid = threadIdx.x;
  const int sw = tid >> 6, lane = tid & 63;
  const int ry = sw >> 1, ch = sw & 1;
  const int g = lane >> 4, c = lane & 15;

  __shared__ __align__(16) unsigned short lds_in[4 * 66 * 64]; // [row][lcol][ci] slot^=(lcol&7)
  __shared__ __align__(16) unsigned short lds_w[64 * 64];      // [co][ci] slot^=(co&7)

  // ---- stage input rows y0-1..y0+2; wave sw -> ci block sw*16..+15 (8 pairs)
  {
    const int rr = lane >> 4;          // 0..3
    const int cb = lane & 15;          // 4 cols each
    const int row = y0 - 1 + rr;
    const bool rok = (row >= 0) && (row < 64);
    #pragma unroll
    for (int pp = 0; pp < 8; ++pp) {
      const int ci0 = sw * 16 + pp * 2;
      f32x4 va = { 0.f, 0.f, 0.f, 0.f }, vb = { 0.f, 0.f, 0.f, 0.f };
      if (rok) {
        va = *(const f32x4*)(src + ((size_t)(bt * 64 + ci0)) * 4096 + row * 64 + cb * 4);
        vb = *(const f32x4*)(src + ((size_t)(bt * 64 + ci0 + 1)) * 4096 + row * 64 + cb * 4);
      }
      char* rbase = (char*)lds_in + (rr * 66) * 128 + (ci0 & 7) * 2;
      const int sl = ci0 >> 3;
      #pragma unroll
      for (int q = 0; q < 4; ++q) {
        int lcol = cb * 4 + q + 1;
        unsigned int pk = (unsigned int)f2bf(va[q]) | ((unsigned int)f2bf(vb[q]) << 16);
        *(unsigned int*)(rbase + lcol * 128 + ((sl ^ (lcol & 7)) * 16)) = pk;
      }
      if (cb == 0)  *(unsigned int*)(rbase + ((sl ^ 0) * 16)) = 0u;              // lcol 0
      if (cb == 15) *(unsigned int*)(rbase + 65 * 128 + ((sl ^ 1) * 16)) = 0u;   // lcol 65
    }
  }

  f32x4 acc[2][4];
  #pragma unroll
  for (int ct = 0; ct < 2; ct++)
    #pragma unroll
    for (int xt = 0; xt < 4; xt++) acc[ct][xt] = (f32x4){ 0.f, 0.f, 0.f, 0.f };

  #pragma unroll 1
  for (int tap = 0; tap < 9; ++tap) {
    __syncthreads();   // prior readers done (tap 0: input staging fence)
    {
      const unsigned short* wp = wt + tap * 4096;
      #pragma unroll
      for (int h = 0; h < 2; ++h) {
        int el = h * 2048 + tid * 8;
        int co = el >> 6, sl = (el & 63) >> 3;
        short8 wv8 = *(const short8*)(wp + el);
        *(short8*)((char*)lds_w + co * 128 + ((sl ^ (co & 7)) * 16)) = wv8;
      }
    }
    __syncthreads();
    const int dy = tap / 3 - 1, dx = tap % 3 - 1;
    const int rowp = ry + 1 + dy;       // 0..3
    #pragma unroll
    for (int kblk = 0; kblk < 2; ++kblk) {
      short8 af[2], bf[4];
      #pragma unroll
      for (int ct = 0; ct < 2; ++ct) {
        int co = ch * 32 + ct * 16 + c;
        af[ct] = *(const short8*)((char*)lds_w + co * 128 + (((kblk * 4 + g) ^ (co & 7)) * 16));
      }
      #pragma unroll
      for (int xt = 0; xt < 4; ++xt) {
        int lcol = xt * 16 + c + dx + 1;
        bf[xt] = *(const short8*)((char*)lds_in + (rowp * 66 + lcol) * 128 + (((kblk * 4 + g) ^ (lcol & 7)) * 16));
      }
      #pragma unroll
      for (int ct = 0; ct < 2; ++ct)
        #pragma unroll
        for (int xt = 0; xt < 4; ++xt)
          acc[ct][xt] = __builtin_amdgcn_mfma_f32_16x16x32_bf16(af[ct], bf[xt], acc[ct][xt], 0, 0, 0);
    }
  }

  // ---- fused epilogue: lane holds C[co=ch*32+ct*16+4g+r][x=xt*16+c], row y
  const int y = y0 + ry;
  if (MODE == 0) {
    const int b = bt / 5, tf = bt % 5;
    const int py = y & 1, gy = y >> 1;
    #pragma unroll
    for (int ct = 0; ct < 2; ++ct)
      #pragma unroll
      for (int r = 0; r < 4; ++r) {
        const int co = ch * 32 + ct * 16 + g * 4 + r;
        const float bv = bias[co];
        #pragma unroll
        for (int xt = 0; xt < 4; ++xt) {
          int x = xt * 16 + c;
          int d = co * 4 + py * 2 + (x & 1);
          int tok = tf * 1024 + gy * 32 + (x >> 1);
          vt[((size_t)(b * DDIM + d)) * NTOK + tok] = f2bf(acc[ct][xt][r] + bv);
        }
      }
  } else {
    #pragma unroll
    for (int ct = 0; ct < 2; ++ct)
      #pragma unroll
      for (int r = 0; r < 4; ++r) {
        const int co = ch * 32 + ct * 16 + g * 4 + r;
        const float bv = bias[co];
        const size_t rowb = ((size_t)(bt * 64 + co)) * 4096 + (size_t)y * 64;
        #pragma unroll
        for (int xt = 0; xt < 4; ++xt) {
          int x = xt * 16 + c;
          dstf[rowb + x] = acc[ct][xt][r] + bv + resid[rowb + x];
        }
      }
  }
}

// ---------------- flash attention partials: 2 i-strips/wave, P overlaid on lds_k (64KB LDS)
// XCD-pinned: flat grid 320; slice = wgid&7 -> (b,jc); all 40 i-tiles of a slice land on
// one XCD (round-robin dispatch), so its 1.25 MB K/V chunk stays L2-resident.
__global__ __launch_bounds__(256, 2) void attn_kernel(
    const unsigned short* __restrict__ qt, const unsigned short* __restrict__ kt,
    const unsigned short* __restrict__ vt, float* __restrict__ po,
    float* __restrict__ pm, float* __restrict__ pl)
{
  const int wgid = blockIdx.x;
  const int slice = wgid & 7;       // XCD id under round-robin dispatch
  const int b = slice >> 2;
  const int jc = slice & 3;
  const int i0 = (wgid >> 3) * 128;
  const int jchunk = NTOK / NJC;    // 1280
  const int tid = threadIdx.x;
  const int w = tid >> 6, lane = tid & 63;
  const int g = lane >> 4, c = lane & 15;

  __shared__ __align__(16) unsigned short lds_k[64 * 256];    // 32 KB [j][d] swizzled; P overlay
  __shared__ __align__(16) unsigned short lds_v[256 * 64];    // 32 KB [d][j] swizzled

  short8 qf[2][8];
  #pragma unroll
  for (int st = 0; st < 2; st++) {
    const unsigned short* qr = qt + ((size_t)(b * NTOK + i0 + w * 32 + st * 16 + c)) * DDIM + g * 8;
    #pragma unroll
    for (int kb = 0; kb < 8; kb++) qf[st][kb] = *(const short8*)(qr + kb * 32);
  }
  f32x4 o[32];
  #pragma unroll
  for (int i = 0; i < 32; i++) o[i] = (f32x4){ 0.f, 0.f, 0.f, 0.f };
  float m[2][4], l[2][4];
  #pragma unroll
  for (int st = 0; st < 2; st++)
    #pragma unroll
    for (int r = 0; r < 4; r++) { m[st][r] = -1e30f; l[st][r] = 0.f; }

  const int sr = tid >> 5, sc = tid & 31;
  const int vdr = tid >> 3, vcc = tid & 7;
  char* pb = (char*)lds_k + w * 4096;   // per-wave P region (overlay)

  const int jbeg = jc * jchunk;
  for (int j0 = jbeg; j0 < jbeg + jchunk; j0 += 64) {
    #pragma unroll
    for (int p = 0; p < 8; p++) {
      int row = sr + p * 8;
      short8 kv = *(const short8*)(kt + ((size_t)(b * NTOK + j0 + row)) * DDIM + sc * 8);
      *(short8*)((char*)lds_k + row * 512 + ((sc ^ (row & 7)) * 16)) = kv;
    }
    #pragma unroll
    for (int p = 0; p < 8; p++) {
      int dd = vdr + p * 32;
      short8 vv = *(const short8*)(vt + ((size_t)(b * DDIM + dd)) * NTOK + j0 + vcc * 8);
      *(short8*)((char*)lds_v + dd * 128 + ((vcc ^ (dd & 7)) * 16)) = vv;
    }
    __syncthreads();

    // S = Q*K^T for both strips; one kf read feeds 2 MFMAs
    f32x4 s0[4], s1[4];
    #pragma unroll
    for (int js = 0; js < 4; js++) {
      s0[js] = (f32x4){ 0.f, 0.f, 0.f, 0.f };
      s1[js] = (f32x4){ 0.f, 0.f, 0.f, 0.f };
      int row = js * 16 + c;
      int sw2 = row & 7;
      #pragma unroll
      for (int kb = 0; kb < 8; kb++) {
        short8 kf = *(const short8*)((char*)lds_k + row * 512 + (((kb * 4 + g) ^ sw2) * 16));
        s0[js] = __builtin_amdgcn_mfma_f32_16x16x32_bf16(qf[0][kb], kf, s0[js], 0, 0, 0);
        s1[js] = __builtin_amdgcn_mfma_f32_16x16x32_bf16(qf[1][kb], kf, s1[js], 0, 0, 0);
      }
    }
    // softmax strip 0 (keep P in regs until barrier)
    float pvv[4][4], alpha[4];
    #pragma unroll
    for (int r = 0; r < 4; r++) {
      float mx = fmaxf(fmaxf(s0[0][r], s0[1][r]), fmaxf(s0[2][r], s0[3][r])) * 0.0625f;
      #pragma unroll
      for (int off = 1; off < 16; off <<= 1) mx = fmaxf(mx, __shfl_xor(mx, off));
      float mn = fmaxf(m[0][r], mx);
      alpha[r] = __expf(m[0][r] - mn);
      float p0 = __expf(s0[0][r] * 0.0625f - mn);
      float p1 = __expf(s0[1][r] * 0.0625f - mn);
      float p2 = __expf(s0[2][r] * 0.0625f - mn);
      float p3 = __expf(s0[3][r] * 0.0625f - mn);
      pvv[0][r] = p0; pvv[1][r] = p1; pvv[2][r] = p2; pvv[3][r] = p3;
      float sum = p0 + p1 + p2 + p3;
      #pragma unroll
      for (int off = 1; off < 16; off <<= 1) sum += __shfl_xor(sum, off);
      l[0][r] = l[0][r] * alpha[r] + sum;
      m[0][r] = mn;
    }
    {
      f32x4 av = { alpha[0], alpha[1], alpha[2], alpha[3] };
      #pragma unroll
      for (int ds = 0; ds < 16; ds++) o[ds] *= av;
    }
    __syncthreads();   // all waves done reading lds_k -> safe to overlay P
    // write P strip 0
    #pragma unroll
    for (int js = 0; js < 4; js++)
      #pragma unroll
      for (int r = 0; r < 4; r++) {
        int row = 4 * g + r;
        int slot = (js * 2 + (c >> 3)) ^ (row & 7);
        *(unsigned short*)(pb + row * 128 + slot * 16 + (c & 7) * 2) = f2bf(pvv[js][r]);
      }
    // softmax strip 1
    #pragma unroll
    for (int r = 0; r < 4; r++) {
      float mx = fmaxf(fmaxf(s1[0][r], s1[1][r]), fmaxf(s1[2][r], s1[3][r])) * 0.0625f;
      #pragma unroll
      for (int off = 1; off < 16; off <<= 1) mx = fmaxf(mx, __shfl_xor(mx, off));
      float mn = fmaxf(m[1][r], mx);
      alpha[r] = __expf(m[1][r] - mn);
      float p0 = __expf(s1[0][r] * 0.0625f - mn);
      float p1 = __expf(s1[1][r] * 0.0625f - mn);
      float p2 = __expf(s1[2][r] * 0.0625f - mn);
      float p3 = __expf(s1[3][r] * 0.0625f - mn);
      pvv[0][r] = p0; pvv[1][r] = p1; pvv[2][r] = p2; pvv[3][r] = p3;
      float sum = p0 + p1 + p2 + p3;
      #pragma unroll
      for (int off = 1; off < 16; off <<= 1) sum += __shfl_xor(sum, off);
      l[1][r] = l[1][r] * alpha[r] + sum;
      m[1][r] = mn;
    }
    {
      f32x4 av = { alpha[0], alpha[1], alpha[2], alpha[3] };
      #pragma unroll
      for (int ds = 0; ds < 16; ds++) o[16 + ds] *= av;
    }
    // write P strip 1
    #pragma unroll
    for (int js = 0; js < 4; js++)
      #pragma unroll
      for (int r = 0; r < 4; r++) {
        int row = 16 + 4 * g + r;
        int slot = (js * 2 + (c >> 3)) ^ (row & 7);
        *(unsigned short*)(pb + row * 128 + slot * 16 + (c & 7) * 2) = f2bf(pvv[js][r]);
      }
    // read P fragments (same-wave DS ordering guarantees write->read)
    short8 pf[2][2];
    #pragma unroll
    for (int st = 0; st < 2; st++)
      #pragma unroll
      for (int k2 = 0; k2 < 2; k2++)
        pf[st][k2] = *(short8*)(pb + (st * 16 + c) * 128 + (((k2 * 4 + g) ^ (c & 7)) * 16));
    // O += P*V; one vf read feeds 2 MFMAs
    #pragma unroll
    for (int ds = 0; ds < 16; ds++) {
      int vrow = ds * 16 + c;
      int sw2 = c & 7;
      #pragma unroll
      for (int k2 = 0; k2 < 2; k2++) {
        short8 vf = *(const short8*)((char*)lds_v + vrow * 128 + (((k2 * 4 + g) ^ sw2) * 16));
        o[ds]      = __builtin_amdgcn_mfma_f32_16x16x32_bf16(pf[0][k2], vf, o[ds], 0, 0, 0);
        o[16 + ds] = __builtin_amdgcn_mfma_f32_16x16x32_bf16(pf[1][k2], vf, o[16 + ds], 0, 0, 0);
      }
    }
    __syncthreads();   // protect lds_k (incl. P overlay) + lds_v before restage
  }
  // ---- epilogue: f32 po, [row][d] layout; each (ds,r) store = 16 lanes x 4B = 64B line
  #pragma unroll
  for (int st = 0; st < 2; st++) {
    const size_t rbase = ((size_t)(b * NJC + jc)) * NTOK + i0 + w * 32 + st * 16;
    #pragma unroll
    for (int ds = 0; ds < 16; ds++)
      #pragma unroll
      for (int r = 0; r < 4; r++)
        po[(rbase + 4 * g + r) * DDIM + ds * 16 + c] = o[st * 16 + ds][r];
    if (c == 0) {
      #pragma unroll
      for (int r = 0; r < 4; r++) {
        pm[rbase + 4 * g + r] = m[st][r];
        pl[rbase + 4 * g + r] = l[st][r];
      }
    }
  }
}

// ---------------- attn combine: online LSE merge of njc f32 partials, fold into feat
__global__ __launch_bounds__(256) void attn_combine(
    const float* __restrict__ po, const float* __restrict__ pm,
    const float* __restrict__ pl, float* __restrict__ feat, int njc)
{
  const int b = blockIdx.y;
  const int i0 = blockIdx.x * 64;
  const int t = threadIdx.x;
  const int row = t >> 2, dq = (t & 3) * 64;
  const int i = i0 + row;

  float M = -1e30f, L = 0.f;
  f32x4 acc[16];
  #pragma unroll
  for (int q = 0; q < 16; q++) acc[q] = (f32x4){ 0.f, 0.f, 0.f, 0.f };

  #pragma unroll 1
  for (int jc = 0; jc < njc; jc++) {
    const size_t rb = ((size_t)(b * njc + jc)) * NTOK + i;
    float mj = pm[rb], lj = pl[rb];
    float mn = fmaxf(M, mj);
    float so = __expf(M - mn), sn = __expf(mj - mn);
    const float* pp = po + rb * DDIM + dq;
    #pragma unroll
    for (int q = 0; q < 16; q++) {
      f32x4 v = *(const f32x4*)(pp + q * 4);
      acc[q] = acc[q] * so + v * sn;
    }
    L = L * so + lj * sn;
    M = mn;
  }
  const float inv = 1.f / L;
  const int tf = i >> 10, jn = i & 1023;
  const int gy = jn >> 5, gx = jn & 31;
  const size_t fb = ((size_t)((b * 5 + tf) * 64)) * 4096 + (2 * gy) * 64 + 2 * gx;
  #pragma unroll
  for (int q = 0; q < 16; q++) {
    f32x4 a = acc[q] * inv;
    int ch = (dq + q * 4) >> 2;
    size_t base = fb + (size_t)ch * 4096;
    feat[base] = a[0]; feat[base + 1] = a[1];
    feat[base + 64] = a[2]; feat[base + 65] = a[3];
  }
}

extern "C" void kernel_launch(void* const* d_in, const int* in_sizes, int n_in,
                              void* d_out, int out_size, void* d_ws, size_t ws_size,
                              hipStream_t stream) {
  const float* x  = (const float*)d_in[0];
  const float* wq = (const float*)d_in[1];
  const float* bq = (const float*)d_in[2];
  const float* wk = (const float*)d_in[3];
  const float* bk = (const float*)d_in[4];
  const float* wv = (const float*)d_in[5];
  const float* bv = (const float*)d_in[6];
  const float* wc = (const float*)d_in[7];
  const float* bc = (const float*)d_in[8];
  float* out = (float*)d_out;

  char* ws = (char*)d_ws;
  unsigned short* qt = (unsigned short*)(ws);              //  5,242,880 B
  unsigned short* kt = (unsigned short*)(ws + 5242880);    //  5,242,880 B
  unsigned short* vt = (unsigned short*)(ws + 10485760);   //  5,242,880 B
  float*          ft = (float*)(ws + 15728640);            // 10,485,760 B
  unsigned short* wtv = (unsigned short*)(ws + 26214400);  //     73,728 B
  unsigned short* wtc = (unsigned short*)(ws + 26288128);  //     73,728 B
  const size_t big_off = 26361856;
  float* po = (float*)(ws + big_off);                      // attn partials f32 [row][d], 41.9 MB

  size_t po_bytes = (size_t)2 * NJC * NTOK * DDIM * 4;
  float* pm = (float*)(ws + big_off + po_bytes);
  float* pl = pm + (size_t)2 * NJC * NTOK;

  wt_gen        <<<dim3(9, 2), 256, 0, stream>>>(wv, wc, wtv, wtc);
  qk_gen        <<<dim3(64, 10), 256, 0, stream>>>(x, wq, bq, wk, bk, qt, kt);
  conv_mfma<0>  <<<dim3(32, 10), 256, 0, stream>>>(x, wtv, bv, nullptr, nullptr, vt);
  attn_kernel   <<<dim3(320), 256, 0, stream>>>(qt, kt, vt, po, pm, pl);
  attn_combine  <<<dim3(80, 2), 256, 0, stream>>>(po, pm, pl, ft, NJC);
  conv_mfma<1>  <<<dim3(32, 10), 256, 0, stream>>>(ft, wtc, bc, x, out, nullptr);
}

// Round 11
// 362.326 us; speedup vs baseline: 1.1429x; 1.1202x over previous
//
#include <hip/hip_runtime.h>
#include <hip/hip_bf16.h>

typedef __attribute__((ext_vector_type(8))) short short8;
typedef __attribute__((ext_vector_type(8))) unsigned short ushort8;
typedef __attribute__((ext_vector_type(4))) unsigned short ushort4v;
typedef __attribute__((ext_vector_type(4))) float f32x4;

#define NTOK 5120
#define DDIM 256
#define NJC 8            // 16 (b,jc) slices; 2 per XCD via chunked mapping

__device__ __forceinline__ unsigned short f2bf(float f) {
  union { float f; unsigned int u; } x; x.f = f;
  unsigned int r = x.u + 0x7FFFu + ((x.u >> 16) & 1u);
  return (unsigned short)(r >> 16);
}
__device__ __forceinline__ float bf2f(unsigned short u) {
  union { unsigned int i; float f; } x; x.i = ((unsigned int)u) << 16; return x.f;
}

// ---------------- Kernel 1: depthwise conv Q,K + unfold -> token-major bf16 [b][5120][256]
__global__ __launch_bounds__(256) void qk_gen(
    const float* __restrict__ xin, const float* __restrict__ wq,
    const float* __restrict__ bq, const float* __restrict__ wk,
    const float* __restrict__ bk, unsigned short* __restrict__ qt,
    unsigned short* __restrict__ kt)
{
  const int ch = blockIdx.x;   // 0..63
  const int bt = blockIdx.y;   // 0..9
  const int b = bt / 5, tf = bt % 5;
  const int tid = threadIdx.x;
  const float* xp = xin + ((size_t)bt * 64 + ch) * 4096;
  float wqv[9], wkv[9];
  #pragma unroll
  for (int i = 0; i < 9; i++) { wqv[i] = wq[ch * 9 + i]; wkv[i] = wk[ch * 9 + i]; }
  const float bqv = bq[ch], bkv = bk[ch];

  #pragma unroll
  for (int p = 0; p < 4; p++) {
    int pid = tid + p * 256;         // patch id in frame (gy*32+gx)
    int gy = pid >> 5, gx = pid & 31;
    float v[4][4];
    #pragma unroll
    for (int r = 0; r < 4; r++) {
      int yy = 2 * gy - 1 + r;
      #pragma unroll
      for (int cc = 0; cc < 4; cc++) {
        int xx = 2 * gx - 1 + cc;
        bool ok = (yy >= 0) && (yy < 64) && (xx >= 0) && (xx < 64);
        v[r][cc] = ok ? xp[yy * 64 + xx] : 0.f;
      }
    }
    unsigned short qo[4], ko[4];
    #pragma unroll
    for (int py = 0; py < 2; py++)
      #pragma unroll
      for (int px = 0; px < 2; px++) {
        float aq = bqv, ak = bkv;
        #pragma unroll
        for (int dy = 0; dy < 3; dy++)
          #pragma unroll
          for (int dx = 0; dx < 3; dx++) {
            float xv = v[py + dy][px + dx];
            aq += wqv[dy * 3 + dx] * xv;
            ak += wkv[dy * 3 + dx] * xv;
          }
        qo[py * 2 + px] = f2bf(aq);
        ko[py * 2 + px] = f2bf(ak);
      }
    size_t base = ((size_t)(b * NTOK + tf * 1024 + pid)) * DDIM + ch * 4;
    ushort4v qv = { qo[0], qo[1], qo[2], qo[3] };
    ushort4v kv = { ko[0], ko[1], ko[2], ko[3] };
    *(ushort4v*)(qt + base) = qv;
    *(ushort4v*)(kt + base) = kv;
  }
}

// ---------------- weight transform: wv/wc [co][ci][9] f32 -> [tap][co][ci] bf16
__global__ __launch_bounds__(256) void wt_gen(
    const float* __restrict__ w0, const float* __restrict__ w1,
    unsigned short* __restrict__ o0, unsigned short* __restrict__ o1)
{
  const int tap = blockIdx.x;            // 0..8
  const float* src = blockIdx.y ? w1 : w0;
  unsigned short* dst = blockIdx.y ? o1 : o0;
  const int t = threadIdx.x;
  #pragma unroll
  for (int i = 0; i < 16; i++) {
    int oi = t + i * 256;                // co*64+ci
    dst[tap * 4096 + oi] = f2bf(src[(size_t)oi * 9 + tap]);
  }
}

// ---------------- implicit-GEMM MFMA conv: 3x3 SAME, 64ci->64co, fused epilogue
template<int MODE>
__global__ __launch_bounds__(256) void conv_mfma(
    const float* __restrict__ src, const unsigned short* __restrict__ wt,
    const float* __restrict__ bias, const float* __restrict__ resid,
    float* __restrict__ dstf, unsigned short* __restrict__ vt)
{
  const int strip = blockIdx.x;  // 0..31
  const int bt = blockIdx.y;     // 0..9
  const int y0 = strip * 2;
  const int tid = threadIdx.x;
  const int sw = tid >> 6, lane = tid & 63;
  const int ry = sw >> 1, ch = sw & 1;
  const int g = lane >> 4, c = lane & 15;

  __shared__ __align__(16) unsigned short lds_in[4 * 66 * 64]; // [row][lcol][ci] slot^=(lcol&7)
  __shared__ __align__(16) unsigned short lds_w[64 * 64];      // [co][ci] slot^=(co&7)

  {
    const int rr = lane >> 4;          // 0..3
    const int cb = lane & 15;          // 4 cols each
    const int row = y0 - 1 + rr;
    const bool rok = (row >= 0) && (row < 64);
    #pragma unroll
    for (int pp = 0; pp < 8; ++pp) {
      const int ci0 = sw * 16 + pp * 2;
      f32x4 va = { 0.f, 0.f, 0.f, 0.f }, vb = { 0.f, 0.f, 0.f, 0.f };
      if (rok) {
        va = *(const f32x4*)(src + ((size_t)(bt * 64 + ci0)) * 4096 + row * 64 + cb * 4);
        vb = *(const f32x4*)(src + ((size_t)(bt * 64 + ci0 + 1)) * 4096 + row * 64 + cb * 4);
      }
      char* rbase = (char*)lds_in + (rr * 66) * 128 + (ci0 & 7) * 2;
      const int sl = ci0 >> 3;
      #pragma unroll
      for (int q = 0; q < 4; ++q) {
        int lcol = cb * 4 + q + 1;
        unsigned int pk = (unsigned int)f2bf(va[q]) | ((unsigned int)f2bf(vb[q]) << 16);
        *(unsigned int*)(rbase + lcol * 128 + ((sl ^ (lcol & 7)) * 16)) = pk;
      }
      if (cb == 0)  *(unsigned int*)(rbase + ((sl ^ 0) * 16)) = 0u;              // lcol 0
      if (cb == 15) *(unsigned int*)(rbase + 65 * 128 + ((sl ^ 1) * 16)) = 0u;   // lcol 65
    }
  }

  f32x4 acc[2][4];
  #pragma unroll
  for (int ct = 0; ct < 2; ct++)
    #pragma unroll
    for (int xt = 0; xt < 4; xt++) acc[ct][xt] = (f32x4){ 0.f, 0.f, 0.f, 0.f };

  #pragma unroll 1
  for (int tap = 0; tap < 9; ++tap) {
    __syncthreads();   // prior readers done (tap 0: input staging fence)
    {
      const unsigned short* wp = wt + tap * 4096;
      #pragma unroll
      for (int h = 0; h < 2; ++h) {
        int el = h * 2048 + tid * 8;
        int co = el >> 6, sl = (el & 63) >> 3;
        short8 wv8 = *(const short8*)(wp + el);
        *(short8*)((char*)lds_w + co * 128 + ((sl ^ (co & 7)) * 16)) = wv8;
      }
    }
    __syncthreads();
    const int dy = tap / 3 - 1, dx = tap % 3 - 1;
    const int rowp = ry + 1 + dy;       // 0..3
    #pragma unroll
    for (int kblk = 0; kblk < 2; ++kblk) {
      short8 af[2], bf[4];
      #pragma unroll
      for (int ct = 0; ct < 2; ++ct) {
        int co = ch * 32 + ct * 16 + c;
        af[ct] = *(const short8*)((char*)lds_w + co * 128 + (((kblk * 4 + g) ^ (co & 7)) * 16));
      }
      #pragma unroll
      for (int xt = 0; xt < 4; ++xt) {
        int lcol = xt * 16 + c + dx + 1;
        bf[xt] = *(const short8*)((char*)lds_in + (rowp * 66 + lcol) * 128 + (((kblk * 4 + g) ^ (lcol & 7)) * 16));
      }
      #pragma unroll
      for (int ct = 0; ct < 2; ++ct)
        #pragma unroll
        for (int xt = 0; xt < 4; ++xt)
          acc[ct][xt] = __builtin_amdgcn_mfma_f32_16x16x32_bf16(af[ct], bf[xt], acc[ct][xt], 0, 0, 0);
    }
  }

  const int y = y0 + ry;
  if (MODE == 0) {
    const int b = bt / 5, tf = bt % 5;
    const int py = y & 1, gy = y >> 1;
    #pragma unroll
    for (int ct = 0; ct < 2; ++ct)
      #pragma unroll
      for (int r = 0; r < 4; ++r) {
        const int co = ch * 32 + ct * 16 + g * 4 + r;
        const float bv = bias[co];
        #pragma unroll
        for (int xt = 0; xt < 4; ++xt) {
          int x = xt * 16 + c;
          int d = co * 4 + py * 2 + (x & 1);
          int tok = tf * 1024 + gy * 32 + (x >> 1);
          vt[((size_t)(b * DDIM + d)) * NTOK + tok] = f2bf(acc[ct][xt][r] + bv);
        }
      }
  } else {
    #pragma unroll
    for (int ct = 0; ct < 2; ++ct)
      #pragma unroll
      for (int r = 0; r < 4; ++r) {
        const int co = ch * 32 + ct * 16 + g * 4 + r;
        const float bv = bias[co];
        const size_t rowb = ((size_t)(bt * 64 + co)) * 4096 + (size_t)y * 64;
        #pragma unroll
        for (int xt = 0; xt < 4; ++xt) {
          int x = xt * 16 + c;
          dstf[rowb + x] = acc[ct][xt][r] + bv + resid[rowb + x];
        }
      }
  }
}

// ---------------- flash attention partials: 2 i-strips/wave, 72KB LDS (separate half-P buffer,
// 2 barriers/tile), slice-pinned chunked grid: each XCD works ~2 K/V slices (L2-resident).
__global__ __launch_bounds__(256, 2) void attn_kernel(
    const unsigned short* __restrict__ qt, const unsigned short* __restrict__ kt,
    const unsigned short* __restrict__ vt, float* __restrict__ po,
    float* __restrict__ pm, float* __restrict__ pl)
{
  const int wgid = blockIdx.x;          // 0..639
  const int chunk = wgid / 320;         // 0..1
  const int within = wgid % 320;
  const int slice = chunk * 8 + (within & 7);   // 0..15 ; slice%8 == wgid%8 -> XCD-pinned
  const int b = slice >> 3;
  const int jc = slice & 7;
  const int i0 = (within >> 3) * 128;   // 0..39 i-tiles
  const int jchunk = NTOK / NJC;        // 640
  const int tid = threadIdx.x;
  const int w = tid >> 6, lane = tid & 63;
  const int g = lane >> 4, c = lane & 15;

  __shared__ __align__(16) unsigned short lds_k[64 * 256];    // 32 KB [j][d] swizzled
  __shared__ __align__(16) unsigned short lds_v[256 * 64];    // 32 KB [d][j] swizzled
  __shared__ __align__(16) unsigned short lds_p[4 * 16 * 64]; //  8 KB per-wave half-P

  short8 qf[2][8];
  #pragma unroll
  for (int st = 0; st < 2; st++) {
    const unsigned short* qr = qt + ((size_t)(b * NTOK + i0 + w * 32 + st * 16 + c)) * DDIM + g * 8;
    #pragma unroll
    for (int kb = 0; kb < 8; kb++) qf[st][kb] = *(const short8*)(qr + kb * 32);
  }
  f32x4 o[32];
  #pragma unroll
  for (int i = 0; i < 32; i++) o[i] = (f32x4){ 0.f, 0.f, 0.f, 0.f };
  float m[2][4], l[2][4];
  #pragma unroll
  for (int st = 0; st < 2; st++)
    #pragma unroll
    for (int r = 0; r < 4; r++) { m[st][r] = -1e30f; l[st][r] = 0.f; }

  const int sr = tid >> 5, sc = tid & 31;
  const int vdr = tid >> 3, vcc = tid & 7;
  char* pb = (char*)lds_p + w * 2048;   // per-wave 2KB half-P

  const int jbeg = jc * jchunk;
  for (int j0 = jbeg; j0 < jbeg + jchunk; j0 += 64) {
    #pragma unroll
    for (int p = 0; p < 8; p++) {
      int row = sr + p * 8;
      short8 kv = *(const short8*)(kt + ((size_t)(b * NTOK + j0 + row)) * DDIM + sc * 8);
      *(short8*)((char*)lds_k + row * 512 + ((sc ^ (row & 7)) * 16)) = kv;
    }
    #pragma unroll
    for (int p = 0; p < 8; p++) {
      int dd = vdr + p * 32;
      short8 vv = *(const short8*)(vt + ((size_t)(b * DDIM + dd)) * NTOK + j0 + vcc * 8);
      *(short8*)((char*)lds_v + dd * 128 + ((vcc ^ (dd & 7)) * 16)) = vv;
    }
    __syncthreads();

    // S = Q*K^T for both strips; one kf read feeds 2 MFMAs
    f32x4 s0[4], s1[4];
    #pragma unroll
    for (int js = 0; js < 4; js++) {
      s0[js] = (f32x4){ 0.f, 0.f, 0.f, 0.f };
      s1[js] = (f32x4){ 0.f, 0.f, 0.f, 0.f };
      int row = js * 16 + c;
      int sw2 = row & 7;
      #pragma unroll
      for (int kb = 0; kb < 8; kb++) {
        short8 kf = *(const short8*)((char*)lds_k + row * 512 + (((kb * 4 + g) ^ sw2) * 16));
        s0[js] = __builtin_amdgcn_mfma_f32_16x16x32_bf16(qf[0][kb], kf, s0[js], 0, 0, 0);
        s1[js] = __builtin_amdgcn_mfma_f32_16x16x32_bf16(qf[1][kb], kf, s1[js], 0, 0, 0);
      }
    }
    // ---- strip 0: softmax -> P (per-wave buffer) -> fragments
    short8 pf[2][2];
    {
      float pvv[4][4], alpha[4];
      #pragma unroll
      for (int r = 0; r < 4; r++) {
        float mx = fmaxf(fmaxf(s0[0][r], s0[1][r]), fmaxf(s0[2][r], s0[3][r])) * 0.0625f;
        #pragma unroll
        for (int off = 1; off < 16; off <<= 1) mx = fmaxf(mx, __shfl_xor(mx, off));
        float mn = fmaxf(m[0][r], mx);
        alpha[r] = __expf(m[0][r] - mn);
        float p0 = __expf(s0[0][r] * 0.0625f - mn);
        float p1 = __expf(s0[1][r] * 0.0625f - mn);
        float p2 = __expf(s0[2][r] * 0.0625f - mn);
        float p3 = __expf(s0[3][r] * 0.0625f - mn);
        pvv[0][r] = p0; pvv[1][r] = p1; pvv[2][r] = p2; pvv[3][r] = p3;
        float sum = p0 + p1 + p2 + p3;
        #pragma unroll
        for (int off = 1; off < 16; off <<= 1) sum += __shfl_xor(sum, off);
        l[0][r] = l[0][r] * alpha[r] + sum;
        m[0][r] = mn;
      }
      f32x4 av = { alpha[0], alpha[1], alpha[2], alpha[3] };
      #pragma unroll
      for (int ds = 0; ds < 16; ds++) o[ds] *= av;
      #pragma unroll
      for (int js = 0; js < 4; js++)
        #pragma unroll
        for (int r = 0; r < 4; r++) {
          int row = 4 * g + r;
          int slot = (js * 2 + (c >> 3)) ^ (row & 7);
          *(unsigned short*)(pb + row * 128 + slot * 16 + (c & 7) * 2) = f2bf(pvv[js][r]);
        }
      #pragma unroll
      for (int k2 = 0; k2 < 2; k2++)
        pf[0][k2] = *(short8*)(pb + c * 128 + (((k2 * 4 + g) ^ (c & 7)) * 16));
    }
    // ---- strip 1: softmax -> P (reuse same buffer; same-wave ordering) -> fragments
    {
      float pvv[4][4], alpha[4];
      #pragma unroll
      for (int r = 0; r < 4; r++) {
        float mx = fmaxf(fmaxf(s1[0][r], s1[1][r]), fmaxf(s1[2][r], s1[3][r])) * 0.0625f;
        #pragma unroll
        for (int off = 1; off < 16; off <<= 1) mx = fmaxf(mx, __shfl_xor(mx, off));
        float mn = fmaxf(m[1][r], mx);
        alpha[r] = __expf(m[1][r] - mn);
        float p0 = __expf(s1[0][r] * 0.0625f - mn);
        float p1 = __expf(s1[1][r] * 0.0625f - mn);
        float p2 = __expf(s1[2][r] * 0.0625f - mn);
        float p3 = __expf(s1[3][r] * 0.0625f - mn);
        pvv[0][r] = p0; pvv[1][r] = p1; pvv[2][r] = p2; pvv[3][r] = p3;
        float sum = p0 + p1 + p2 + p3;
        #pragma unroll
        for (int off = 1; off < 16; off <<= 1) sum += __shfl_xor(sum, off);
        l[1][r] = l[1][r] * alpha[r] + sum;
        m[1][r] = mn;
      }
      f32x4 av = { alpha[0], alpha[1], alpha[2], alpha[3] };
      #pragma unroll
      for (int ds = 0; ds < 16; ds++) o[16 + ds] *= av;
      #pragma unroll
      for (int js = 0; js < 4; js++)
        #pragma unroll
        for (int r = 0; r < 4; r++) {
          int row = 4 * g + r;
          int slot = (js * 2 + (c >> 3)) ^ (row & 7);
          *(unsigned short*)(pb + row * 128 + slot * 16 + (c & 7) * 2) = f2bf(pvv[js][r]);
        }
      #pragma unroll
      for (int k2 = 0; k2 < 2; k2++)
        pf[1][k2] = *(short8*)(pb + c * 128 + (((k2 * 4 + g) ^ (c & 7)) * 16));
    }
    // O += P*V; one vf read feeds 2 MFMAs
    #pragma unroll
    for (int ds = 0; ds < 16; ds++) {
      int vrow = ds * 16 + c;
      int sw2 = c & 7;
      #pragma unroll
      for (int k2 = 0; k2 < 2; k2++) {
        short8 vf = *(const short8*)((char*)lds_v + vrow * 128 + (((k2 * 4 + g) ^ sw2) * 16));
        o[ds]      = __builtin_amdgcn_mfma_f32_16x16x32_bf16(pf[0][k2], vf, o[ds], 0, 0, 0);
        o[16 + ds] = __builtin_amdgcn_mfma_f32_16x16x32_bf16(pf[1][k2], vf, o[16 + ds], 0, 0, 0);
      }
    }
    __syncthreads();   // protect lds_k/lds_v before restage
  }
  // ---- epilogue: f32 po [row][d]; each (ds,r) store = 16 lanes x 4B = 64B line
  #pragma unroll
  for (int st = 0; st < 2; st++) {
    const size_t rbase = ((size_t)(b * NJC + jc)) * NTOK + i0 + w * 32 + st * 16;
    #pragma unroll
    for (int ds = 0; ds < 16; ds++)
      #pragma unroll
      for (int r = 0; r < 4; r++)
        po[(rbase + 4 * g + r) * DDIM + ds * 16 + c] = o[st * 16 + ds][r];
    if (c == 0) {
      #pragma unroll
      for (int r = 0; r < 4; r++) {
        pm[rbase + 4 * g + r] = m[st][r];
        pl[rbase + 4 * g + r] = l[st][r];
      }
    }
  }
}

// ---------------- attn combine: online LSE merge of njc f32 partials, fold into feat
__global__ __launch_bounds__(256) void attn_combine(
    const float* __restrict__ po, const float* __restrict__ pm,
    const float* __restrict__ pl, float* __restrict__ feat, int njc)
{
  const int b = blockIdx.y;
  const int i0 = blockIdx.x * 64;
  const int t = threadIdx.x;
  const int row = t >> 2, dq = (t & 3) * 64;
  const int i = i0 + row;

  float M = -1e30f, L = 0.f;
  f32x4 acc[16];
  #pragma unroll
  for (int q = 0; q < 16; q++) acc[q] = (f32x4){ 0.f, 0.f, 0.f, 0.f };

  #pragma unroll 1
  for (int jc = 0; jc < njc; jc++) {
    const size_t rb = ((size_t)(b * njc + jc)) * NTOK + i;
    float mj = pm[rb], lj = pl[rb];
    float mn = fmaxf(M, mj);
    float so = __expf(M - mn), sn = __expf(mj - mn);
    const float* pp = po + rb * DDIM + dq;
    #pragma unroll
    for (int q = 0; q < 16; q++) {
      f32x4 v = *(const f32x4*)(pp + q * 4);
      acc[q] = acc[q] * so + v * sn;
    }
    L = L * so + lj * sn;
    M = mn;
  }
  const float inv = 1.f / L;
  const int tf = i >> 10, jn = i & 1023;
  const int gy = jn >> 5, gx = jn & 31;
  const size_t fb = ((size_t)((b * 5 + tf) * 64)) * 4096 + (2 * gy) * 64 + 2 * gx;
  #pragma unroll
  for (int q = 0; q < 16; q++) {
    f32x4 a = acc[q] * inv;
    int ch = (dq + q * 4) >> 2;
    size_t base = fb + (size_t)ch * 4096;
    feat[base] = a[0]; feat[base + 1] = a[1];
    feat[base + 64] = a[2]; feat[base + 65] = a[3];
  }
}

extern "C" void kernel_launch(void* const* d_in, const int* in_sizes, int n_in,
                              void* d_out, int out_size, void* d_ws, size_t ws_size,
                              hipStream_t stream) {
  const float* x  = (const float*)d_in[0];
  const float* wq = (const float*)d_in[1];
  const float* bq = (const float*)d_in[2];
  const float* wk = (const float*)d_in[3];
  const float* bk = (const float*)d_in[4];
  const float* wv = (const float*)d_in[5];
  const float* bv = (const float*)d_in[6];
  const float* wc = (const float*)d_in[7];
  const float* bc = (const float*)d_in[8];
  float* out = (float*)d_out;

  char* ws = (char*)d_ws;
  unsigned short* qt = (unsigned short*)(ws);              //  5,242,880 B
  unsigned short* kt = (unsigned short*)(ws + 5242880);    //  5,242,880 B
  unsigned short* vt = (unsigned short*)(ws + 10485760);   //  5,242,880 B
  float*          ft = (float*)(ws + 15728640);            // 10,485,760 B
  unsigned short* wtv = (unsigned short*)(ws + 26214400);  //     73,728 B
  unsigned short* wtc = (unsigned short*)(ws + 26288128);  //     73,728 B
  const size_t big_off = 26361856;
  float* po = (float*)(ws + big_off);                      // attn partials f32, 83.9 MB

  size_t po_bytes = (size_t)2 * NJC * NTOK * DDIM * 4;
  float* pm = (float*)(ws + big_off + po_bytes);
  float* pl = pm + (size_t)2 * NJC * NTOK;

  wt_gen        <<<dim3(9, 2), 256, 0, stream>>>(wv, wc, wtv, wtc);
  qk_gen        <<<dim3(64, 10), 256, 0, stream>>>(x, wq, bq, wk, bk, qt, kt);
  conv_mfma<0>  <<<dim3(32, 10), 256, 0, stream>>>(x, wtv, bv, nullptr, nullptr, vt);
  attn_kernel   <<<dim3(640), 256, 0, stream>>>(qt, kt, vt, po, pm, pl);
  attn_combine  <<<dim3(80, 2), 256, 0, stream>>>(po, pm, pl, ft, NJC);
  conv_mfma<1>  <<<dim3(32, 10), 256, 0, stream>>>(ft, wtc, bc, x, out, nullptr);
}

// Round 12
// 246.028 us; speedup vs baseline: 1.6831x; 1.4727x over previous
//
#include <hip/hip_runtime.h>
#include <hip/hip_bf16.h>

typedef __attribute__((ext_vector_type(8))) short short8;
typedef __attribute__((ext_vector_type(8))) unsigned short ushort8;
typedef __attribute__((ext_vector_type(4))) unsigned short ushort4v;
typedef __attribute__((ext_vector_type(4))) float f32x4;

#define NTOK 5120
#define DDIM 256
#define NJC 8            // 16 (b,jc) slices; 2 per XCD via chunked mapping

__device__ __forceinline__ unsigned short f2bf(float f) {
  union { float f; unsigned int u; } x; x.f = f;
  unsigned int r = x.u + 0x7FFFu + ((x.u >> 16) & 1u);
  return (unsigned short)(r >> 16);
}
__device__ __forceinline__ float bf2f(unsigned short u) {
  union { unsigned int i; float f; } x; x.i = ((unsigned int)u) << 16; return x.f;
}

// ---------------- Kernel 1: depthwise conv Q,K + unfold -> token-major bf16 [b][5120][256]
__global__ __launch_bounds__(256) void qk_gen(
    const float* __restrict__ xin, const float* __restrict__ wq,
    const float* __restrict__ bq, const float* __restrict__ wk,
    const float* __restrict__ bk, unsigned short* __restrict__ qt,
    unsigned short* __restrict__ kt)
{
  const int ch = blockIdx.x;   // 0..63
  const int bt = blockIdx.y;   // 0..9
  const int b = bt / 5, tf = bt % 5;
  const int tid = threadIdx.x;
  const float* xp = xin + ((size_t)bt * 64 + ch) * 4096;
  float wqv[9], wkv[9];
  #pragma unroll
  for (int i = 0; i < 9; i++) { wqv[i] = wq[ch * 9 + i]; wkv[i] = wk[ch * 9 + i]; }
  const float bqv = bq[ch], bkv = bk[ch];

  #pragma unroll
  for (int p = 0; p < 4; p++) {
    int pid = tid + p * 256;         // patch id in frame (gy*32+gx)
    int gy = pid >> 5, gx = pid & 31;
    float v[4][4];
    #pragma unroll
    for (int r = 0; r < 4; r++) {
      int yy = 2 * gy - 1 + r;
      #pragma unroll
      for (int cc = 0; cc < 4; cc++) {
        int xx = 2 * gx - 1 + cc;
        bool ok = (yy >= 0) && (yy < 64) && (xx >= 0) && (xx < 64);
        v[r][cc] = ok ? xp[yy * 64 + xx] : 0.f;
      }
    }
    unsigned short qo[4], ko[4];
    #pragma unroll
    for (int py = 0; py < 2; py++)
      #pragma unroll
      for (int px = 0; px < 2; px++) {
        float aq = bqv, ak = bkv;
        #pragma unroll
        for (int dy = 0; dy < 3; dy++)
          #pragma unroll
          for (int dx = 0; dx < 3; dx++) {
            float xv = v[py + dy][px + dx];
            aq += wqv[dy * 3 + dx] * xv;
            ak += wkv[dy * 3 + dx] * xv;
          }
        qo[py * 2 + px] = f2bf(aq);
        ko[py * 2 + px] = f2bf(ak);
      }
    size_t base = ((size_t)(b * NTOK + tf * 1024 + pid)) * DDIM + ch * 4;
    ushort4v qv = { qo[0], qo[1], qo[2], qo[3] };
    ushort4v kv = { ko[0], ko[1], ko[2], ko[3] };
    *(ushort4v*)(qt + base) = qv;
    *(ushort4v*)(kt + base) = kv;
  }
}

// ---------------- weight transform: wv/wc [co][ci][9] f32 -> [tap][co][ci] bf16
__global__ __launch_bounds__(256) void wt_gen(
    const float* __restrict__ w0, const float* __restrict__ w1,
    unsigned short* __restrict__ o0, unsigned short* __restrict__ o1)
{
  const int tap = blockIdx.x;            // 0..8
  const float* src = blockIdx.y ? w1 : w0;
  unsigned short* dst = blockIdx.y ? o1 : o0;
  const int t = threadIdx.x;
  #pragma unroll
  for (int i = 0; i < 16; i++) {
    int oi = t + i * 256;                // co*64+ci
    dst[tap * 4096 + oi] = f2bf(src[(size_t)oi * 9 + tap]);
  }
}

// ---------------- implicit-GEMM MFMA conv: 3x3 SAME, 64ci->64co, fused epilogue
template<int MODE>
__global__ __launch_bounds__(256) void conv_mfma(
    const float* __restrict__ src, const unsigned short* __restrict__ wt,
    const float* __restrict__ bias, const float* __restrict__ resid,
    float* __restrict__ dstf, unsigned short* __restrict__ vt)
{
  const int strip = blockIdx.x;  // 0..31
  const int bt = blockIdx.y;     // 0..9
  const int y0 = strip * 2;
  const int tid = threadIdx.x;
  const int sw = tid >> 6, lane = tid & 63;
  const int ry = sw >> 1, ch = sw & 1;
  const int g = lane >> 4, c = lane & 15;

  __shared__ __align__(16) unsigned short lds_in[4 * 66 * 64]; // [row][lcol][ci] slot^=(lcol&7)
  __shared__ __align__(16) unsigned short lds_w[64 * 64];      // [co][ci] slot^=(co&7)

  {
    const int rr = lane >> 4;          // 0..3
    const int cb = lane & 15;          // 4 cols each
    const int row = y0 - 1 + rr;
    const bool rok = (row >= 0) && (row < 64);
    #pragma unroll
    for (int pp = 0; pp < 8; ++pp) {
      const int ci0 = sw * 16 + pp * 2;
      f32x4 va = { 0.f, 0.f, 0.f, 0.f }, vb = { 0.f, 0.f, 0.f, 0.f };
      if (rok) {
        va = *(const f32x4*)(src + ((size_t)(bt * 64 + ci0)) * 4096 + row * 64 + cb * 4);
        vb = *(const f32x4*)(src + ((size_t)(bt * 64 + ci0 + 1)) * 4096 + row * 64 + cb * 4);
      }
      char* rbase = (char*)lds_in + (rr * 66) * 128 + (ci0 & 7) * 2;
      const int sl = ci0 >> 3;
      #pragma unroll
      for (int q = 0; q < 4; ++q) {
        int lcol = cb * 4 + q + 1;
        unsigned int pk = (unsigned int)f2bf(va[q]) | ((unsigned int)f2bf(vb[q]) << 16);
        *(unsigned int*)(rbase + lcol * 128 + ((sl ^ (lcol & 7)) * 16)) = pk;
      }
      if (cb == 0)  *(unsigned int*)(rbase + ((sl ^ 0) * 16)) = 0u;              // lcol 0
      if (cb == 15) *(unsigned int*)(rbase + 65 * 128 + ((sl ^ 1) * 16)) = 0u;   // lcol 65
    }
  }

  f32x4 acc[2][4];
  #pragma unroll
  for (int ct = 0; ct < 2; ct++)
    #pragma unroll
    for (int xt = 0; xt < 4; xt++) acc[ct][xt] = (f32x4){ 0.f, 0.f, 0.f, 0.f };

  #pragma unroll 1
  for (int tap = 0; tap < 9; ++tap) {
    __syncthreads();   // prior readers done (tap 0: input staging fence)
    {
      const unsigned short* wp = wt + tap * 4096;
      #pragma unroll
      for (int h = 0; h < 2; ++h) {
        int el = h * 2048 + tid * 8;
        int co = el >> 6, sl = (el & 63) >> 3;
        short8 wv8 = *(const short8*)(wp + el);
        *(short8*)((char*)lds_w + co * 128 + ((sl ^ (co & 7)) * 16)) = wv8;
      }
    }
    __syncthreads();
    const int dy = tap / 3 - 1, dx = tap % 3 - 1;
    const int rowp = ry + 1 + dy;       // 0..3
    #pragma unroll
    for (int kblk = 0; kblk < 2; ++kblk) {
      short8 af[2], bf[4];
      #pragma unroll
      for (int ct = 0; ct < 2; ++ct) {
        int co = ch * 32 + ct * 16 + c;
        af[ct] = *(const short8*)((char*)lds_w + co * 128 + (((kblk * 4 + g) ^ (co & 7)) * 16));
      }
      #pragma unroll
      for (int xt = 0; xt < 4; ++xt) {
        int lcol = xt * 16 + c + dx + 1;
        bf[xt] = *(const short8*)((char*)lds_in + (rowp * 66 + lcol) * 128 + (((kblk * 4 + g) ^ (lcol & 7)) * 16));
      }
      #pragma unroll
      for (int ct = 0; ct < 2; ++ct)
        #pragma unroll
        for (int xt = 0; xt < 4; ++xt)
          acc[ct][xt] = __builtin_amdgcn_mfma_f32_16x16x32_bf16(af[ct], bf[xt], acc[ct][xt], 0, 0, 0);
    }
  }

  const int y = y0 + ry;
  if (MODE == 0) {
    const int b = bt / 5, tf = bt % 5;
    const int py = y & 1, gy = y >> 1;
    #pragma unroll
    for (int ct = 0; ct < 2; ++ct)
      #pragma unroll
      for (int r = 0; r < 4; ++r) {
        const int co = ch * 32 + ct * 16 + g * 4 + r;
        const float bv = bias[co];
        #pragma unroll
        for (int xt = 0; xt < 4; ++xt) {
          int x = xt * 16 + c;
          int d = co * 4 + py * 2 + (x & 1);
          int tok = tf * 1024 + gy * 32 + (x >> 1);
          vt[((size_t)(b * DDIM + d)) * NTOK + tok] = f2bf(acc[ct][xt][r] + bv);
        }
      }
  } else {
    #pragma unroll
    for (int ct = 0; ct < 2; ++ct)
      #pragma unroll
      for (int r = 0; r < 4; ++r) {
        const int co = ch * 32 + ct * 16 + g * 4 + r;
        const float bv = bias[co];
        const size_t rowb = ((size_t)(bt * 64 + co)) * 4096 + (size_t)y * 64;
        #pragma unroll
        for (int xt = 0; xt < 4; ++xt) {
          int x = xt * 16 + c;
          dstf[rowb + x] = acc[ct][xt][r] + bv + resid[rowb + x];
        }
      }
  }
}

// ---------------- flash attention partials: 2 i-strips/wave, 72KB LDS, 2 barriers/tile.
// NO min-waves clause: VGPR must stay ~212-256 (2 waves/SIMD) with ZERO spill — the
// (256,2) clause in R5-R11 capped VGPR at 128 and spilled ~100 regs/thread to scratch.
__global__ __launch_bounds__(256) void attn_kernel(
    const unsigned short* __restrict__ qt, const unsigned short* __restrict__ kt,
    const unsigned short* __restrict__ vt, float* __restrict__ po,
    float* __restrict__ pm, float* __restrict__ pl)
{
  const int wgid = blockIdx.x;          // 0..639
  const int chunk = wgid / 320;         // 0..1
  const int within = wgid % 320;
  const int slice = chunk * 8 + (within & 7);   // 0..15 ; slice%8 == wgid%8 -> XCD-pinned
  const int b = slice >> 3;
  const int jc = slice & 7;
  const int i0 = (within >> 3) * 128;   // 0..39 i-tiles
  const int jchunk = NTOK / NJC;        // 640
  const int tid = threadIdx.x;
  const int w = tid >> 6, lane = tid & 63;
  const int g = lane >> 4, c = lane & 15;

  __shared__ __align__(16) unsigned short lds_k[64 * 256];    // 32 KB [j][d] swizzled
  __shared__ __align__(16) unsigned short lds_v[256 * 64];    // 32 KB [d][j] swizzled
  __shared__ __align__(16) unsigned short lds_p[4 * 16 * 64]; //  8 KB per-wave half-P

  short8 qf[2][8];
  #pragma unroll
  for (int st = 0; st < 2; st++) {
    const unsigned short* qr = qt + ((size_t)(b * NTOK + i0 + w * 32 + st * 16 + c)) * DDIM + g * 8;
    #pragma unroll
    for (int kb = 0; kb < 8; kb++) qf[st][kb] = *(const short8*)(qr + kb * 32);
  }
  f32x4 o[32];
  #pragma unroll
  for (int i = 0; i < 32; i++) o[i] = (f32x4){ 0.f, 0.f, 0.f, 0.f };
  float m[2][4], l[2][4];
  #pragma unroll
  for (int st = 0; st < 2; st++)
    #pragma unroll
    for (int r = 0; r < 4; r++) { m[st][r] = -1e30f; l[st][r] = 0.f; }

  const int sr = tid >> 5, sc = tid & 31;
  const int vdr = tid >> 3, vcc = tid & 7;
  char* pb = (char*)lds_p + w * 2048;   // per-wave 2KB half-P

  const int jbeg = jc * jchunk;
  for (int j0 = jbeg; j0 < jbeg + jchunk; j0 += 64) {
    #pragma unroll
    for (int p = 0; p < 8; p++) {
      int row = sr + p * 8;
      short8 kv = *(const short8*)(kt + ((size_t)(b * NTOK + j0 + row)) * DDIM + sc * 8);
      *(short8*)((char*)lds_k + row * 512 + ((sc ^ (row & 7)) * 16)) = kv;
    }
    #pragma unroll
    for (int p = 0; p < 8; p++) {
      int dd = vdr + p * 32;
      short8 vv = *(const short8*)(vt + ((size_t)(b * DDIM + dd)) * NTOK + j0 + vcc * 8);
      *(short8*)((char*)lds_v + dd * 128 + ((vcc ^ (dd & 7)) * 16)) = vv;
    }
    __syncthreads();

    // S = Q*K^T for both strips; one kf read feeds 2 MFMAs
    f32x4 s0[4], s1[4];
    #pragma unroll
    for (int js = 0; js < 4; js++) {
      s0[js] = (f32x4){ 0.f, 0.f, 0.f, 0.f };
      s1[js] = (f32x4){ 0.f, 0.f, 0.f, 0.f };
      int row = js * 16 + c;
      int sw2 = row & 7;
      #pragma unroll
      for (int kb = 0; kb < 8; kb++) {
        short8 kf = *(const short8*)((char*)lds_k + row * 512 + (((kb * 4 + g) ^ sw2) * 16));
        s0[js] = __builtin_amdgcn_mfma_f32_16x16x32_bf16(qf[0][kb], kf, s0[js], 0, 0, 0);
        s1[js] = __builtin_amdgcn_mfma_f32_16x16x32_bf16(qf[1][kb], kf, s1[js], 0, 0, 0);
      }
    }
    // ---- strip 0: softmax -> P (per-wave buffer) -> fragments
    short8 pf[2][2];
    {
      float pvv[4][4], alpha[4];
      #pragma unroll
      for (int r = 0; r < 4; r++) {
        float mx = fmaxf(fmaxf(s0[0][r], s0[1][r]), fmaxf(s0[2][r], s0[3][r])) * 0.0625f;
        #pragma unroll
        for (int off = 1; off < 16; off <<= 1) mx = fmaxf(mx, __shfl_xor(mx, off));
        float mn = fmaxf(m[0][r], mx);
        alpha[r] = __expf(m[0][r] - mn);
        float p0 = __expf(s0[0][r] * 0.0625f - mn);
        float p1 = __expf(s0[1][r] * 0.0625f - mn);
        float p2 = __expf(s0[2][r] * 0.0625f - mn);
        float p3 = __expf(s0[3][r] * 0.0625f - mn);
        pvv[0][r] = p0; pvv[1][r] = p1; pvv[2][r] = p2; pvv[3][r] = p3;
        float sum = p0 + p1 + p2 + p3;
        #pragma unroll
        for (int off = 1; off < 16; off <<= 1) sum += __shfl_xor(sum, off);
        l[0][r] = l[0][r] * alpha[r] + sum;
        m[0][r] = mn;
      }
      f32x4 av = { alpha[0], alpha[1], alpha[2], alpha[3] };
      #pragma unroll
      for (int ds = 0; ds < 16; ds++) o[ds] *= av;
      #pragma unroll
      for (int js = 0; js < 4; js++)
        #pragma unroll
        for (int r = 0; r < 4; r++) {
          int row = 4 * g + r;
          int slot = (js * 2 + (c >> 3)) ^ (row & 7);
          *(unsigned short*)(pb + row * 128 + slot * 16 + (c & 7) * 2) = f2bf(pvv[js][r]);
        }
      #pragma unroll
      for (int k2 = 0; k2 < 2; k2++)
        pf[0][k2] = *(short8*)(pb + c * 128 + (((k2 * 4 + g) ^ (c & 7)) * 16));
    }
    // ---- strip 1: softmax -> P (reuse same buffer; same-wave ordering) -> fragments
    {
      float pvv[4][4], alpha[4];
      #pragma unroll
      for (int r = 0; r < 4; r++) {
        float mx = fmaxf(fmaxf(s1[0][r], s1[1][r]), fmaxf(s1[2][r], s1[3][r])) * 0.0625f;
        #pragma unroll
        for (int off = 1; off < 16; off <<= 1) mx = fmaxf(mx, __shfl_xor(mx, off));
        float mn = fmaxf(m[1][r], mx);
        alpha[r] = __expf(m[1][r] - mn);
        float p0 = __expf(s1[0][r] * 0.0625f - mn);
        float p1 = __expf(s1[1][r] * 0.0625f - mn);
        float p2 = __expf(s1[2][r] * 0.0625f - mn);
        float p3 = __expf(s1[3][r] * 0.0625f - mn);
        pvv[0][r] = p0; pvv[1][r] = p1; pvv[2][r] = p2; pvv[3][r] = p3;
        float sum = p0 + p1 + p2 + p3;
        #pragma unroll
        for (int off = 1; off < 16; off <<= 1) sum += __shfl_xor(sum, off);
        l[1][r] = l[1][r] * alpha[r] + sum;
        m[1][r] = mn;
      }
      f32x4 av = { alpha[0], alpha[1], alpha[2], alpha[3] };
      #pragma unroll
      for (int ds = 0; ds < 16; ds++) o[16 + ds] *= av;
      #pragma unroll
      for (int js = 0; js < 4; js++)
        #pragma unroll
        for (int r = 0; r < 4; r++) {
          int row = 4 * g + r;
          int slot = (js * 2 + (c >> 3)) ^ (row & 7);
          *(unsigned short*)(pb + row * 128 + slot * 16 + (c & 7) * 2) = f2bf(pvv[js][r]);
        }
      #pragma unroll
      for (int k2 = 0; k2 < 2; k2++)
        pf[1][k2] = *(short8*)(pb + c * 128 + (((k2 * 4 + g) ^ (c & 7)) * 16));
    }
    // O += P*V; one vf read feeds 2 MFMAs
    #pragma unroll
    for (int ds = 0; ds < 16; ds++) {
      int vrow = ds * 16 + c;
      int sw2 = c & 7;
      #pragma unroll
      for (int k2 = 0; k2 < 2; k2++) {
        short8 vf = *(const short8*)((char*)lds_v + vrow * 128 + (((k2 * 4 + g) ^ sw2) * 16));
        o[ds]      = __builtin_amdgcn_mfma_f32_16x16x32_bf16(pf[0][k2], vf, o[ds], 0, 0, 0);
        o[16 + ds] = __builtin_amdgcn_mfma_f32_16x16x32_bf16(pf[1][k2], vf, o[16 + ds], 0, 0, 0);
      }
    }
    __syncthreads();   // protect lds_k/lds_v before restage
  }
  // ---- epilogue: f32 po [row][d]; each (ds,r) store = 16 lanes x 4B = 64B line
  #pragma unroll
  for (int st = 0; st < 2; st++) {
    const size_t rbase = ((size_t)(b * NJC + jc)) * NTOK + i0 + w * 32 + st * 16;
    #pragma unroll
    for (int ds = 0; ds < 16; ds++)
      #pragma unroll
      for (int r = 0; r < 4; r++)
        po[(rbase + 4 * g + r) * DDIM + ds * 16 + c] = o[st * 16 + ds][r];
    if (c == 0) {
      #pragma unroll
      for (int r = 0; r < 4; r++) {
        pm[rbase + 4 * g + r] = m[st][r];
        pl[rbase + 4 * g + r] = l[st][r];
      }
    }
  }
}

// ---------------- attn combine: online LSE merge of njc f32 partials, fold into feat
__global__ __launch_bounds__(256) void attn_combine(
    const float* __restrict__ po, const float* __restrict__ pm,
    const float* __restrict__ pl, float* __restrict__ feat, int njc)
{
  const int b = blockIdx.y;
  const int i0 = blockIdx.x * 64;
  const int t = threadIdx.x;
  const int row = t >> 2, dq = (t & 3) * 64;
  const int i = i0 + row;

  float M = -1e30f, L = 0.f;
  f32x4 acc[16];
  #pragma unroll
  for (int q = 0; q < 16; q++) acc[q] = (f32x4){ 0.f, 0.f, 0.f, 0.f };

  #pragma unroll 1
  for (int jc = 0; jc < njc; jc++) {
    const size_t rb = ((size_t)(b * njc + jc)) * NTOK + i;
    float mj = pm[rb], lj = pl[rb];
    float mn = fmaxf(M, mj);
    float so = __expf(M - mn), sn = __expf(mj - mn);
    const float* pp = po + rb * DDIM + dq;
    #pragma unroll
    for (int q = 0; q < 16; q++) {
      f32x4 v = *(const f32x4*)(pp + q * 4);
      acc[q] = acc[q] * so + v * sn;
    }
    L = L * so + lj * sn;
    M = mn;
  }
  const float inv = 1.f / L;
  const int tf = i >> 10, jn = i & 1023;
  const int gy = jn >> 5, gx = jn & 31;
  const size_t fb = ((size_t)((b * 5 + tf) * 64)) * 4096 + (2 * gy) * 64 + 2 * gx;
  #pragma unroll
  for (int q = 0; q < 16; q++) {
    f32x4 a = acc[q] * inv;
    int ch = (dq + q * 4) >> 2;
    size_t base = fb + (size_t)ch * 4096;
    feat[base] = a[0]; feat[base + 1] = a[1];
    feat[base + 64] = a[2]; feat[base + 65] = a[3];
  }
}

extern "C" void kernel_launch(void* const* d_in, const int* in_sizes, int n_in,
                              void* d_out, int out_size, void* d_ws, size_t ws_size,
                              hipStream_t stream) {
  const float* x  = (const float*)d_in[0];
  const float* wq = (const float*)d_in[1];
  const float* bq = (const float*)d_in[2];
  const float* wk = (const float*)d_in[3];
  const float* bk = (const float*)d_in[4];
  const float* wv = (const float*)d_in[5];
  const float* bv = (const float*)d_in[6];
  const float* wc = (const float*)d_in[7];
  const float* bc = (const float*)d_in[8];
  float* out = (float*)d_out;

  char* ws = (char*)d_ws;
  unsigned short* qt = (unsigned short*)(ws);              //  5,242,880 B
  unsigned short* kt = (unsigned short*)(ws + 5242880);    //  5,242,880 B
  unsigned short* vt = (unsigned short*)(ws + 10485760);   //  5,242,880 B
  float*          ft = (float*)(ws + 15728640);            // 10,485,760 B
  unsigned short* wtv = (unsigned short*)(ws + 26214400);  //     73,728 B
  unsigned short* wtc = (unsigned short*)(ws + 26288128);  //     73,728 B
  const size_t big_off = 26361856;
  float* po = (float*)(ws + big_off);                      // attn partials f32, 83.9 MB

  size_t po_bytes = (size_t)2 * NJC * NTOK * DDIM * 4;
  float* pm = (float*)(ws + big_off + po_bytes);
  float* pl = pm + (size_t)2 * NJC * NTOK;

  wt_gen        <<<dim3(9, 2), 256, 0, stream>>>(wv, wc, wtv, wtc);
  qk_gen        <<<dim3(64, 10), 256, 0, stream>>>(x, wq, bq, wk, bk, qt, kt);
  conv_mfma<0>  <<<dim3(32, 10), 256, 0, stream>>>(x, wtv, bv, nullptr, nullptr, vt);
  attn_kernel   <<<dim3(640), 256, 0, stream>>>(qt, kt, vt, po, pm, pl);
  attn_combine  <<<dim3(80, 2), 256, 0, stream>>>(po, pm, pl, ft, NJC);
  conv_mfma<1>  <<<dim3(32, 10), 256, 0, stream>>>(ft, wtc, bc, x, out, nullptr);
}